// Round 9
// baseline (135.664 us; speedup 1.0000x reference)
//
#include <hip/hip_runtime.h>
#include <cstdint>

typedef float  f32x4  __attribute__((ext_vector_type(4)));
typedef float  f32x16 __attribute__((ext_vector_type(16)));
typedef short  short8 __attribute__((ext_vector_type(8)));
typedef _Float16 half4 __attribute__((ext_vector_type(4)));
typedef _Float16 half8 __attribute__((ext_vector_type(8)));
typedef _Float16 half2v __attribute__((ext_vector_type(2)));

// ---------- helpers ----------
__device__ __forceinline__ unsigned short f2bf(float f) {
    unsigned u = __builtin_bit_cast(unsigned, f);
    u += 0x7FFFu + ((u >> 16) & 1u);   // RNE
    return (unsigned short)(u >> 16);
}

__device__ __forceinline__ half2v pkrtz(float a, float b) {
    return __builtin_bit_cast(half2v, __builtin_amdgcn_cvt_pkrtz(a, b));
}

// ---------- kernel 1: weights fp32 -> bf16 (3 x 256 x 256) ----------
__global__ void wconv_kernel(const float* __restrict__ wq,
                             const float* __restrict__ wk,
                             const float* __restrict__ wv,
                             unsigned short* __restrict__ Wb) {
    int p = blockIdx.x >> 8;                       // 0..2
    int i = ((blockIdx.x & 255) << 8) + threadIdx.x; // 0..65535
    const float* src = (p == 0) ? wq : ((p == 1) ? wk : wv);
    Wb[(p << 16) + i] = f2bf(src[i]);
}

// ---------- kernel 2: build X0 [B][S][256] bf16 ----------
__global__ void build_x0_kernel(const float* __restrict__ x,
                                unsigned short* __restrict__ X0) {
    __shared__ float tile[32][33];
    int b  = blockIdx.z;
    int ct = blockIdx.y;     // 0..7  (32 channels each)
    int st = blockIdx.x;     // 0..31 (32 s each)
    int tid = threadIdx.x;
    int lo = tid & 31, hi = tid >> 5;   // 8 rows per pass

    if (ct < 7) {
        #pragma unroll
        for (int r = 0; r < 4; ++r) {
            int c = hi + 8 * r;
            tile[c][lo] = x[((b * 224 + ct * 32 + c) << 10) + st * 32 + lo];
        }
        __syncthreads();
        #pragma unroll
        for (int r = 0; r < 4; ++r) {
            int s_loc = hi + 8 * r;
            X0[(((b << 10) + st * 32 + s_loc) << 8) + ct * 32 + lo] = f2bf(tile[lo][s_loc]);
        }
    } else {
        #pragma unroll
        for (int r = 0; r < 4; ++r) {
            int s_loc = hi + 8 * r;
            int s = st * 32 + s_loc;
            int h = s >> 5, w = s & 31;
            int ch = lo;  // 0..31 -> pe channel
            int i = (ch < 16) ? (ch * 32 + h) : ((ch - 16) * 32 + w);
            int l = i >> 4, e = i & 15;
            float val = 0.f;
            if (l > 0) {
                float ang = (float)l * powf(10000.f, -(float)(e >> 1) * 0.125f);
                val = (e & 1) ? cosf(ang) : sinf(ang);
            }
            X0[(((b << 10) + s) << 8) + 224 + ch] = f2bf(val);
        }
    }
}

// ---------- kernel 3: QKV projection, LDS-staged ----------
__global__ __launch_bounds__(256) void proj_kernel(
        const unsigned short* __restrict__ X0,
        const unsigned short* __restrict__ Wb,
        const float* __restrict__ bq, const float* __restrict__ bk,
        const float* __restrict__ bv,
        unsigned short* __restrict__ Q, unsigned short* __restrict__ K,
        _Float16* __restrict__ V) {
    __shared__ __align__(16) char Xlds[32768];   // 64 s-rows x 512B
    __shared__ __align__(16) char Wlds[32768];   // 64 o-rows x 512B

    int pb = blockIdx.z; int proj = pb >> 5; int b = pb & 31;
    int tid = threadIdx.x; int w = tid >> 6; int l = tid & 63;
    int g = l >> 4, c = l & 15;
    int sb = blockIdx.x * 64;           // s-tile base
    int o0 = blockIdx.y * 64;           // o-tile base
    const unsigned short* Wp = Wb + (proj << 16);
    const float* bias = (proj == 0) ? bq : ((proj == 1) ? bk : bv);

    // ---- stage X0 tile: 2048 16B chunks, coalesced, swizzled ----
    const unsigned short* Xg = &X0[((b << 10) + sb) << 8];
    #pragma unroll
    for (int p = 0; p < 8; ++p) {
        int ch = p * 256 + tid;
        int row = ch >> 5, cc = ch & 31;
        short8 v = *(const short8*)&Xg[(row << 8) + cc * 8];
        *(short8*)&Xlds[((ch & ~31) | (cc ^ (row & 7))) << 4] = v;
    }
    // ---- stage W tile: 2048 16B chunks ----
    const unsigned short* Wg = &Wp[o0 << 8];
    #pragma unroll
    for (int p = 0; p < 8; ++p) {
        int ch = p * 256 + tid;
        int row = ch >> 5, cc = ch & 31;
        short8 v = *(const short8*)&Wg[(row << 8) + cc * 8];
        *(short8*)&Wlds[((ch & ~31) | (cc ^ (row & 7))) << 4] = v;
    }
    __syncthreads();

    // ---- A fragments (this wave's 16 s-rows) into registers ----
    int s0 = sb + w * 16;
    const char* abase = &Xlds[(w * 16 + c) * 512];
    short8 af[8];
    #pragma unroll
    for (int kk = 0; kk < 8; ++kk)
        af[kk] = *(const short8*)&abase[((kk * 4 + g) ^ (c & 7)) << 4];

    f32x4 acc[4];
    #pragma unroll
    for (int ot = 0; ot < 4; ++ot) acc[ot] = (f32x4){0.f, 0.f, 0.f, 0.f};

    __builtin_amdgcn_s_setprio(1);
    #pragma unroll
    for (int ot = 0; ot < 4; ++ot) {
        const char* bbase = &Wlds[(ot * 16 + c) * 512];
        #pragma unroll
        for (int kk = 0; kk < 8; ++kk) {
            short8 bfr = *(const short8*)&bbase[((kk * 4 + g) ^ (c & 7)) << 4];
            acc[ot] = __builtin_amdgcn_mfma_f32_16x16x32_bf16(af[kk], bfr, acc[ot], 0, 0, 0);
        }
    }
    __builtin_amdgcn_s_setprio(0);

    #pragma unroll
    for (int ot = 0; ot < 4; ++ot) {
        int o = o0 + ot * 16 + c;
        float bb = bias[o];
        if (proj < 2) {
            unsigned short* dst = (proj == 0) ? Q : K;
            #pragma unroll
            for (int r = 0; r < 4; ++r) {
                float v = fmaxf(acc[ot][r] + bb, 0.f);
                int s = s0 + 4 * g + r;
                dst[(((b << 10) + s) << 8) + o] = f2bf(v);
            }
        } else {
            half4 hv;
            #pragma unroll
            for (int r = 0; r < 4; ++r)
                hv[r] = (_Float16)fmaxf(acc[ot][r] + bb, 0.f);
            *(half4*)&V[(((b << 8) + o) << 10) + s0 + 4 * g] = hv;
        }
    }
}

// ---------- kernel 4: causal attention, 32x32 MFMA, pipelined dbuf ----------
// 512 blocks x 128 threads. Block = (batch XCD-grouped, 64-row q-tile),
// wave w owns 32 q-rows. t-tile = 32; K/V double-buffered in LDS (64KB),
// staged via global_load_lds with pre-swizzled global source.
// Pipeline per tile: [vmcnt(0)+s_barrier] -> issue stage(t+1) -> compute(t).
__global__ __launch_bounds__(128, 1) void attn_kernel(
        const unsigned short* __restrict__ Q,
        const unsigned short* __restrict__ K,
        const _Float16* __restrict__ V,
        float* __restrict__ out) {
    __shared__ __align__(16) char Klds[2][16384];   // 32 t-rows x 512B each
    __shared__ __align__(16) char Vlds[2][16384];   // 256 v-rows x 64B each

    int bid = blockIdx.x;
    int xcd  = bid & 7;
    int qv   = (bid >> 3) & 7;
    int bhi  = (bid >> 6) & 3;
    int hf   = bid >> 8;
    int b  = (bhi << 3) | xcd;
    int qt = hf ? qv : (15 - qv);

    int w  = threadIdx.x >> 6;
    int l  = threadIdx.x & 63;
    int lo = l >> 5, cs = l & 31;
    int s0 = (qt << 6) + (w << 5);
    int sg = s0 + cs;                   // this lane's s column

    // ---- Q fragments: 16 x short8 (64 VGPR), B-operand layout ----
    short8 qf[16];
    const unsigned short* Qrow = &Q[(((b << 10) + s0 + cs) << 8) + lo * 8];
    #pragma unroll
    for (int kc = 0; kc < 16; ++kc)
        qf[kc] = *(const short8*)&Qrow[kc * 16];

    f32x16 acc[8];
    #pragma unroll
    for (int i = 0; i < 8; ++i)
        #pragma unroll
        for (int r = 0; r < 16; ++r) acc[i][r] = 0.f;
    float m = -1e30f, lsum = 0.f;

    const unsigned short* Kb_ = &K[(size_t)b << 18];
    const _Float16*       Vb_ = &V[(size_t)b << 18];

    int nt = 2 * qt + 2;
    int mydiag = 2 * qt + w;

    // stage tile t into buffer bufi (each wave issues its 16 chunks)
    auto stage = [&](int t, int bufi) {
        int t0 = t << 5;
        #pragma unroll
        for (int j = 0; j < 8; ++j) {
            int q = (((j << 1) | w) << 6) + l;
            int trow = q >> 5;
            int cl = (q & 31) ^ (trow & 7);
            __builtin_amdgcn_global_load_lds(
                (const unsigned int*)&Kb_[((t0 + trow) << 8) + cl * 8],
                (unsigned int*)(Klds[bufi] + (((j << 1) | w) << 10)), 16, 0, 0);
        }
        #pragma unroll
        for (int j = 0; j < 8; ++j) {
            int q = (((j << 1) | w) << 6) + l;
            int v = q >> 2;
            int cl = (q & 3) ^ ((v >> 1) & 3);
            __builtin_amdgcn_global_load_lds(
                (const unsigned int*)&Vb_[(v << 10) + t0 + cl * 8],
                (unsigned int*)(Vlds[bufi] + (((j << 1) | w) << 10)), 16, 0, 0);
        }
    };

    stage(0, 0);

    for (int t = 0; t < nt; ++t) {
        int t0 = t << 5;
        // tile t's loads done + all waves synced (no full-drain __syncthreads)
        asm volatile("s_waitcnt vmcnt(0)\n\ts_barrier" ::: "memory");
        if (t + 1 < nt) stage(t + 1, (t + 1) & 1);   // overlap with compute(t)

        if (t <= mydiag) {
            const char* Kl = Klds[t & 1];
            const char* Vl = Vlds[t & 1];
            // ---- QK^T: D[t][s], four accumulator chains ----
            f32x16 sc0, sc1, sc2, sc3;
            #pragma unroll
            for (int r = 0; r < 16; ++r) { sc0[r] = 0.f; sc1[r] = 0.f; sc2[r] = 0.f; sc3[r] = 0.f; }
            #pragma unroll
            for (int kc = 0; kc < 16; kc += 4) {
                int p0 = (cs << 5) + ((((kc + 0) << 1) | lo) ^ (cs & 7));
                int p1 = (cs << 5) + ((((kc + 1) << 1) | lo) ^ (cs & 7));
                int p2 = (cs << 5) + ((((kc + 2) << 1) | lo) ^ (cs & 7));
                int p3 = (cs << 5) + ((((kc + 3) << 1) | lo) ^ (cs & 7));
                short8 a0 = *(const short8*)&Kl[p0 << 4];
                short8 a1 = *(const short8*)&Kl[p1 << 4];
                short8 a2 = *(const short8*)&Kl[p2 << 4];
                short8 a3 = *(const short8*)&Kl[p3 << 4];
                sc0 = __builtin_amdgcn_mfma_f32_32x32x16_bf16(a0, qf[kc + 0], sc0, 0, 0, 0);
                sc1 = __builtin_amdgcn_mfma_f32_32x32x16_bf16(a1, qf[kc + 1], sc1, 0, 0, 0);
                sc2 = __builtin_amdgcn_mfma_f32_32x32x16_bf16(a2, qf[kc + 2], sc2, 0, 0, 0);
                sc3 = __builtin_amdgcn_mfma_f32_32x32x16_bf16(a3, qf[kc + 3], sc3, 0, 0, 0);
            }
            // ---- scale + mask ----
            bool diag = (t == mydiag);
            float sv[16];
            #pragma unroll
            for (int r = 0; r < 16; ++r) {
                sv[r] = ((sc0[r] + sc1[r]) + (sc2[r] + sc3[r])) * 0.0625f;
                if (diag) {
                    int tg = t0 + (r & 3) + 8 * (r >> 2) + 4 * lo;
                    if (tg > sg) sv[r] = -1e30f;
                }
            }
            // ---- online softmax (T13 defer-max) ----
            float tm = sv[0];
            #pragma unroll
            for (int r = 1; r < 16; ++r) tm = fmaxf(tm, sv[r]);
            tm = fmaxf(tm, __shfl_xor(tm, 32));
            if (!__all((int)(tm <= m + 8.f))) {
                float mnew = fmaxf(m, tm);
                float alpha = __expf(m - mnew);
                m = mnew;
                lsum *= alpha;
                #pragma unroll
                for (int i = 0; i < 8; ++i)
                    #pragma unroll
                    for (int r = 0; r < 16; ++r) acc[i][r] *= alpha;
            }
            float p[16]; float ps = 0.f;
            #pragma unroll
            for (int r = 0; r < 16; ++r) { p[r] = __expf(sv[r] - m); ps += p[r]; }
            ps += __shfl_xor(ps, 32);
            lsum += ps;
            // ---- pack P to f16 pairs ----
            half2v ph[8];
            #pragma unroll
            for (int i = 0; i < 8; ++i)
                ph[i] = pkrtz(p[2 * i], p[2 * i + 1]);
            // ---- PV, tc = 0 (t 0..15 of tile) ----
            {
                half2v po[4];
                #pragma unroll
                for (int i = 0; i < 4; ++i)
                    po[i] = __builtin_bit_cast(half2v,
                        __shfl_xor(__builtin_bit_cast(int, ph[i]), 32));
                half2v e0 = lo ? po[2] : ph[0];
                half2v e1 = lo ? po[3] : ph[1];
                half2v e2 = lo ? ph[2] : po[0];
                half2v e3 = lo ? ph[3] : po[1];
                half8 frag = {e0[0], e0[1], e1[0], e1[1], e2[0], e2[1], e3[0], e3[1]};
                #pragma unroll
                for (int vt = 0; vt < 8; ++vt) {
                    int v = (vt << 5) + cs;
                    int pos = (v << 2) + (lo ^ ((v >> 1) & 3));
                    half8 vf = *(const half8*)&Vl[pos << 4];
                    acc[vt] = __builtin_amdgcn_mfma_f32_32x32x16_f16(vf, frag, acc[vt], 0, 0, 0);
                }
            }
            // ---- PV, tc = 1 (t 16..31 of tile) ----
            {
                half2v po[4];
                #pragma unroll
                for (int i = 0; i < 4; ++i)
                    po[i] = __builtin_bit_cast(half2v,
                        __shfl_xor(__builtin_bit_cast(int, ph[4 + i]), 32));
                half2v e0 = lo ? po[2] : ph[4];
                half2v e1 = lo ? po[3] : ph[5];
                half2v e2 = lo ? ph[6] : po[0];
                half2v e3 = lo ? ph[7] : po[1];
                half8 frag = {e0[0], e0[1], e1[0], e1[1], e2[0], e2[1], e3[0], e3[1]};
                #pragma unroll
                for (int vt = 0; vt < 8; ++vt) {
                    int v = (vt << 5) + cs;
                    int pos = (v << 2) + ((2 | lo) ^ ((v >> 1) & 3));
                    half8 vf = *(const half8*)&Vl[pos << 4];
                    acc[vt] = __builtin_amdgcn_mfma_f32_32x32x16_f16(vf, frag, acc[vt], 0, 0, 0);
                }
            }
        }
    }

    // ---- epilogue ----
    float rl = 1.f / lsum;
    #pragma unroll
    for (int vt = 0; vt < 8; ++vt) {
        #pragma unroll
        for (int r = 0; r < 16; ++r) {
            int vrow = (vt << 5) + (r & 3) + 8 * (r >> 2) + 4 * lo;
            out[(((b << 8) + vrow) << 10) + sg] = acc[vt][r] * rl;
        }
    }
}

// ---------- launcher ----------
extern "C" void kernel_launch(void* const* d_in, const int* in_sizes, int n_in,
                              void* d_out, int out_size, void* d_ws, size_t ws_size,
                              hipStream_t stream) {
    const float* x  = (const float*)d_in[0];
    const float* wq = (const float*)d_in[1];
    const float* bq = (const float*)d_in[2];
    const float* wk = (const float*)d_in[3];
    const float* bk = (const float*)d_in[4];
    const float* wv = (const float*)d_in[5];
    const float* bv = (const float*)d_in[6];
    float* out = (float*)d_out;

    char* ws = (char*)d_ws;
    unsigned short* Wb = (unsigned short*)ws;                       // 393,216 B
    unsigned short* X0 = (unsigned short*)(ws + 393216);            // 16,777,216 B
    unsigned short* Qb = (unsigned short*)(ws + 393216 + 16777216);
    unsigned short* Kb = (unsigned short*)(ws + 393216 + 2 * 16777216);
    _Float16*       Vb = (_Float16*)     (ws + 393216 + 3 * 16777216);

    wconv_kernel<<<768, 256, 0, stream>>>(wq, wk, wv, Wb);
    build_x0_kernel<<<dim3(32, 8, 32), 256, 0, stream>>>(x, X0);
    proj_kernel<<<dim3(16, 4, 96), 256, 0, stream>>>(X0, Wb, bq, bk, bv, Qb, Kb, Vb);
    attn_kernel<<<512, 128, 0, stream>>>(Qb, Kb, Vb, out);
}

// Round 10
// 127.393 us; speedup vs baseline: 1.0649x; 1.0649x over previous
//
#include <hip/hip_runtime.h>
#include <cstdint>

typedef float  f32x4  __attribute__((ext_vector_type(4)));
typedef short  short8 __attribute__((ext_vector_type(8)));
typedef _Float16 half4 __attribute__((ext_vector_type(4)));

// ---------- helpers ----------
__device__ __forceinline__ unsigned short f2bf(float f) {
    unsigned u = __builtin_bit_cast(unsigned, f);
    u += 0x7FFFu + ((u >> 16) & 1u);   // RNE
    return (unsigned short)(u >> 16);
}

// ---------- kernel 1: weights fp32 -> bf16 (3 x 256 x 256) ----------
__global__ void wconv_kernel(const float* __restrict__ wq,
                             const float* __restrict__ wk,
                             const float* __restrict__ wv,
                             unsigned short* __restrict__ Wb) {
    int p = blockIdx.x >> 8;                       // 0..2
    int i = ((blockIdx.x & 255) << 8) + threadIdx.x; // 0..65535
    const float* src = (p == 0) ? wq : ((p == 1) ? wk : wv);
    Wb[(p << 16) + i] = f2bf(src[i]);
}

// ---------- kernel 2: build X0 [B][S][256] bf16 ----------
__global__ void build_x0_kernel(const float* __restrict__ x,
                                unsigned short* __restrict__ X0) {
    __shared__ float tile[32][33];
    int b  = blockIdx.z;
    int ct = blockIdx.y;     // 0..7  (32 channels each)
    int st = blockIdx.x;     // 0..31 (32 s each)
    int tid = threadIdx.x;
    int lo = tid & 31, hi = tid >> 5;   // 8 rows per pass

    if (ct < 7) {
        #pragma unroll
        for (int r = 0; r < 4; ++r) {
            int c = hi + 8 * r;
            tile[c][lo] = x[((b * 224 + ct * 32 + c) << 10) + st * 32 + lo];
        }
        __syncthreads();
        #pragma unroll
        for (int r = 0; r < 4; ++r) {
            int s_loc = hi + 8 * r;
            X0[(((b << 10) + st * 32 + s_loc) << 8) + ct * 32 + lo] = f2bf(tile[lo][s_loc]);
        }
    } else {
        #pragma unroll
        for (int r = 0; r < 4; ++r) {
            int s_loc = hi + 8 * r;
            int s = st * 32 + s_loc;
            int h = s >> 5, w = s & 31;
            int ch = lo;  // 0..31 -> pe channel
            int i = (ch < 16) ? (ch * 32 + h) : ((ch - 16) * 32 + w);
            int l = i >> 4, e = i & 15;
            float val = 0.f;
            if (l > 0) {
                float ang = (float)l * powf(10000.f, -(float)(e >> 1) * 0.125f);
                val = (e & 1) ? cosf(ang) : sinf(ang);
            }
            X0[(((b << 10) + s) << 8) + 224 + ch] = f2bf(val);
        }
    }
}

// ---------- kernel 3: QKV projection, LDS-staged ----------
__global__ __launch_bounds__(256) void proj_kernel(
        const unsigned short* __restrict__ X0,
        const unsigned short* __restrict__ Wb,
        const float* __restrict__ bq, const float* __restrict__ bk,
        const float* __restrict__ bv,
        unsigned short* __restrict__ Q, unsigned short* __restrict__ K,
        _Float16* __restrict__ V) {
    __shared__ __align__(16) char Xlds[32768];   // 64 s-rows x 512B
    __shared__ __align__(16) char Wlds[32768];   // 64 o-rows x 512B

    int pb = blockIdx.z; int proj = pb >> 5; int b = pb & 31;
    int tid = threadIdx.x; int w = tid >> 6; int l = tid & 63;
    int g = l >> 4, c = l & 15;
    int sb = blockIdx.x * 64;           // s-tile base
    int o0 = blockIdx.y * 64;           // o-tile base
    const unsigned short* Wp = Wb + (proj << 16);
    const float* bias = (proj == 0) ? bq : ((proj == 1) ? bk : bv);

    // ---- stage X0 tile: 2048 16B chunks, coalesced, swizzled ----
    const unsigned short* Xg = &X0[((b << 10) + sb) << 8];
    #pragma unroll
    for (int p = 0; p < 8; ++p) {
        int ch = p * 256 + tid;
        int row = ch >> 5, cc = ch & 31;
        short8 v = *(const short8*)&Xg[(row << 8) + cc * 8];
        *(short8*)&Xlds[((ch & ~31) | (cc ^ (row & 7))) << 4] = v;
    }
    // ---- stage W tile: 2048 16B chunks ----
    const unsigned short* Wg = &Wp[o0 << 8];
    #pragma unroll
    for (int p = 0; p < 8; ++p) {
        int ch = p * 256 + tid;
        int row = ch >> 5, cc = ch & 31;
        short8 v = *(const short8*)&Wg[(row << 8) + cc * 8];
        *(short8*)&Wlds[((ch & ~31) | (cc ^ (row & 7))) << 4] = v;
    }
    __syncthreads();

    // ---- A fragments (this wave's 16 s-rows) into registers ----
    int s0 = sb + w * 16;
    const char* abase = &Xlds[(w * 16 + c) * 512];
    short8 af[8];
    #pragma unroll
    for (int kk = 0; kk < 8; ++kk)
        af[kk] = *(const short8*)&abase[((kk * 4 + g) ^ (c & 7)) << 4];

    f32x4 acc[4];
    #pragma unroll
    for (int ot = 0; ot < 4; ++ot) acc[ot] = (f32x4){0.f, 0.f, 0.f, 0.f};

    __builtin_amdgcn_s_setprio(1);
    #pragma unroll
    for (int ot = 0; ot < 4; ++ot) {
        const char* bbase = &Wlds[(ot * 16 + c) * 512];
        #pragma unroll
        for (int kk = 0; kk < 8; ++kk) {
            short8 bfr = *(const short8*)&bbase[((kk * 4 + g) ^ (c & 7)) << 4];
            acc[ot] = __builtin_amdgcn_mfma_f32_16x16x32_bf16(af[kk], bfr, acc[ot], 0, 0, 0);
        }
    }
    __builtin_amdgcn_s_setprio(0);

    #pragma unroll
    for (int ot = 0; ot < 4; ++ot) {
        int o = o0 + ot * 16 + c;
        float bb = bias[o];
        if (proj < 2) {
            unsigned short* dst = (proj == 0) ? Q : K;
            #pragma unroll
            for (int r = 0; r < 4; ++r) {
                float v = fmaxf(acc[ot][r] + bb, 0.f);
                int s = s0 + 4 * g + r;
                dst[(((b << 10) + s) << 8) + o] = f2bf(v);
            }
        } else {
            half4 hv;
            #pragma unroll
            for (int r = 0; r < 4; ++r)
                hv[r] = (_Float16)fmaxf(acc[ot][r] + bb, 0.f);
            *(half4*)&V[(((b << 8) + o) << 10) + s0 + 4 * g] = hv;
        }
    }
}

// ---------- kernel 4: causal attention ----------
// 512 blocks x 256 threads (4 waves x 16 q-rows = 64-row q-tile).
// t-tile = 32; K (16KB, XOR row&7 on 16B chunks) + V (16KB, rows 64B,
// 16B chunks XOR (v>>2)&3) double-buffered (64KB) -> 2 blocks/CU = 2 waves/SIMD.
// Staged via global_load_lds (pre-swizzled global source, linear LDS dest).
// Pipeline: [vmcnt(0)+s_barrier] -> issue stage(t+1) -> compute(t).
__global__ __launch_bounds__(256, 2) void attn_kernel(
        const unsigned short* __restrict__ Q,
        const unsigned short* __restrict__ K,
        const _Float16* __restrict__ V,
        float* __restrict__ out) {
    __shared__ __align__(16) char Klds[2][16384];   // 32 t-rows x 512B
    __shared__ __align__(16) char Vlds[2][16384];   // 256 v-rows x 64B

    int bid = blockIdx.x;
    int xcd  = bid & 7;
    int qv   = (bid >> 3) & 7;
    int bhi  = (bid >> 6) & 3;
    int hf   = bid >> 8;
    int b  = (bhi << 3) | xcd;
    int qt = hf ? qv : (15 - qv);       // 0..15, 64-row q-tile

    int tid = threadIdx.x; int w = tid >> 6; int l = tid & 63;
    int g = l >> 4, c = l & 15;
    int s0 = (qt << 6) + (w << 4);      // this wave's 16 q-rows

    // ---- Q fragments ----
    short8 qf[8];
    #pragma unroll
    for (int kk = 0; kk < 8; ++kk)
        qf[kk] = *(const short8*)&Q[(((b << 10) + s0 + c) << 8) + kk * 32 + g * 8];

    float m = -1e30f, lsum = 0.f;
    f32x4 acc[16];
    #pragma unroll
    for (int i = 0; i < 16; ++i) acc[i] = (f32x4){0.f, 0.f, 0.f, 0.f};

    const unsigned short* Kb_ = &K[(size_t)b << 18];
    const _Float16*       Vb_ = &V[(size_t)b << 18];

    int nt = 2 * qt + 2;                // 32-wide t-tiles
    int dt = 2 * qt + (w >> 1);         // this wave's diagonal t-tile

    // stage tile t into buffer bufi: 256 threads x (4 K + 4 V) chunks
    auto stage = [&](int t, int bufi) {
        int t0 = t << 5;
        #pragma unroll
        for (int j = 0; j < 4; ++j) {
            int ch = (j << 8) + tid;            // 0..1023
            int trow = ch >> 5;
            int cl = (ch & 31) ^ (trow & 7);
            __builtin_amdgcn_global_load_lds(
                (const unsigned int*)&Kb_[((t0 + trow) << 8) + cl * 8],
                (unsigned int*)(Klds[bufi] + ((j << 8) + (w << 6)) * 16), 16, 0, 0);
        }
        #pragma unroll
        for (int j = 0; j < 4; ++j) {
            int ch = (j << 8) + tid;            // 0..1023
            int v = ch >> 2;
            int c16 = (ch & 3) ^ ((v >> 2) & 3);
            __builtin_amdgcn_global_load_lds(
                (const unsigned int*)&Vb_[(v << 10) + t0 + c16 * 8],
                (unsigned int*)(Vlds[bufi] + ((j << 8) + (w << 6)) * 16), 16, 0, 0);
        }
    };

    stage(0, 0);

    for (int t = 0; t < nt; ++t) {
        asm volatile("s_waitcnt vmcnt(0)\n\ts_barrier" ::: "memory");
        if (t + 1 < nt) stage(t + 1, (t + 1) & 1);   // overlap with compute(t)
        if (t > dt) continue;                        // done; keep barrier cadence

        const char* Kl = Klds[t & 1];
        const char* Vl = Vlds[t & 1];
        #pragma unroll
        for (int sub = 0; sub < 2; ++sub) {
            // wave's rows: sub-tile alignment -> diag sub is sub==(w&1)
            bool dmask = (t == dt) && (sub == (w & 1));
            if ((t == dt) && !(w & 1) && sub == 1) break;   // fully above diag
            int toff = sub << 4;
            // ---- QK^T from LDS (16x16x32, 2 chains) ----
            f32x4 sc0 = {0.f,0.f,0.f,0.f}, sc1 = {0.f,0.f,0.f,0.f};
            const char* kbase = &Kl[(toff + c) * 512];
            __builtin_amdgcn_s_setprio(1);
            #pragma unroll
            for (int kk = 0; kk < 8; kk += 2) {
                short8 a0 = *(const short8*)&kbase[(((kk * 4 + g)       ^ (c & 7)) << 4)];
                short8 a1 = *(const short8*)&kbase[((((kk + 1) * 4 + g) ^ (c & 7)) << 4)];
                sc0 = __builtin_amdgcn_mfma_f32_16x16x32_bf16(a0, qf[kk], sc0, 0, 0, 0);
                sc1 = __builtin_amdgcn_mfma_f32_16x16x32_bf16(a1, qf[kk + 1], sc1, 0, 0, 0);
            }
            __builtin_amdgcn_s_setprio(0);
            // ---- V fragments from LDS (issued before softmax chain) ----
            // lane reads V[vrow = vt*16+c][(t-sub) 8B piece g] : vrow 64B row,
            // 16B chunk (sub*2 + g/2) ^ ((vrow>>2)&3), 8B half (g&1)
            half4 vf[16];
            #pragma unroll
            for (int vt = 0; vt < 16; ++vt) {
                int v = vt * 16 + c;
                int c16 = ((sub << 1) + (g >> 1)) ^ ((v >> 2) & 3);
                vf[vt] = *(const half4*)&Vl[(v << 6) + (c16 << 4) + (g & 1) * 8];
            }
            // ---- online softmax (T13 defer-max) ----
            float sv[4];
            #pragma unroll
            for (int r = 0; r < 4; ++r) sv[r] = (sc0[r] + sc1[r]) * 0.0625f;
            if (dmask) {
                #pragma unroll
                for (int r = 0; r < 4; ++r)
                    if (4 * g + r > c) sv[r] = -1e30f;
            }
            float tm = fmaxf(fmaxf(sv[0], sv[1]), fmaxf(sv[2], sv[3]));
            tm = fmaxf(tm, __shfl_xor(tm, 16));
            tm = fmaxf(tm, __shfl_xor(tm, 32));
            if (!__all((int)(tm <= m + 8.f))) {
                float mnew = fmaxf(m, tm);
                float alpha = __expf(m - mnew);
                m = mnew;
                lsum *= alpha;
                #pragma unroll
                for (int i = 0; i < 16; ++i) acc[i] *= alpha;
            }
            float p[4], ps = 0.f;
            #pragma unroll
            for (int r = 0; r < 4; ++r) { p[r] = __expf(sv[r] - m); ps += p[r]; }
            ps += __shfl_xor(ps, 16);
            ps += __shfl_xor(ps, 32);
            lsum += ps;
            half4 pb;
            #pragma unroll
            for (int r = 0; r < 4; ++r) pb[r] = (_Float16)p[r];
            // ---- PV (16x16x16 f16, P layout matches B-operand directly) ----
            __builtin_amdgcn_s_setprio(1);
            #pragma unroll
            for (int vt = 0; vt < 16; ++vt)
                acc[vt] = __builtin_amdgcn_mfma_f32_16x16x16f16(vf[vt], pb, acc[vt], 0, 0, 0);
            __builtin_amdgcn_s_setprio(0);
        }
    }

    // ---- epilogue ----
    float rl = 1.f / lsum;
    #pragma unroll
    for (int vt = 0; vt < 16; ++vt) {
        #pragma unroll
        for (int r = 0; r < 4; ++r)
            out[(((b << 8) + vt * 16 + 4 * g + r) << 10) + s0 + c] = acc[vt][r] * rl;
    }
}

// ---------- launcher ----------
extern "C" void kernel_launch(void* const* d_in, const int* in_sizes, int n_in,
                              void* d_out, int out_size, void* d_ws, size_t ws_size,
                              hipStream_t stream) {
    const float* x  = (const float*)d_in[0];
    const float* wq = (const float*)d_in[1];
    const float* bq = (const float*)d_in[2];
    const float* wk = (const float*)d_in[3];
    const float* bk = (const float*)d_in[4];
    const float* wv = (const float*)d_in[5];
    const float* bv = (const float*)d_in[6];
    float* out = (float*)d_out;

    char* ws = (char*)d_ws;
    unsigned short* Wb = (unsigned short*)ws;                       // 393,216 B
    unsigned short* X0 = (unsigned short*)(ws + 393216);            // 16,777,216 B
    unsigned short* Qb = (unsigned short*)(ws + 393216 + 16777216);
    unsigned short* Kb = (unsigned short*)(ws + 393216 + 2 * 16777216);
    _Float16*       Vb = (_Float16*)     (ws + 393216 + 3 * 16777216);

    wconv_kernel<<<768, 256, 0, stream>>>(wq, wk, wv, Wb);
    build_x0_kernel<<<dim3(32, 8, 32), 256, 0, stream>>>(x, X0);
    proj_kernel<<<dim3(16, 4, 96), 256, 0, stream>>>(X0, Wb, bq, bk, bv, Qb, Kb, Vb);
    attn_kernel<<<512, 256, 0, stream>>>(Qb, Kb, Vb, out);
}